// Round 8
// baseline (1116.297 us; speedup 1.0000x reference)
//
#include <hip/hip_runtime.h>
#include <hip/hip_bf16.h>
#include <math.h>

#define B_    4
#define S_    4096
#define D_    2048
#define F_    8192
#define KTOP  2048
#define ALPHA 0.1f

typedef __attribute__((ext_vector_type(8))) short short8;
typedef __attribute__((ext_vector_type(4))) float floatx4;

typedef const __attribute__((address_space(1))) void* gas_ptr;
typedef __attribute__((address_space(3))) void* las_ptr;

__device__ __forceinline__ short f2bf(float f) {
    unsigned u = __float_as_uint(f);
    unsigned r = u + 0x7FFFu + ((u >> 16) & 1u);
    return (short)(r >> 16);
}
__device__ __forceinline__ float bf2f(short s) {
    return __uint_as_float(((unsigned)(unsigned short)s) << 16);
}

// ---------------- router logits + copy hidden -> out ----------------
__global__ void router_copy_kernel(const float* __restrict__ h, const float* __restrict__ wr,
                                   float* __restrict__ out, float* __restrict__ logits) {
    int tok = blockIdx.x;
    const float4* hp = (const float4*)(h + (size_t)tok * D_);
    float4* op = (float4*)(out + (size_t)tok * D_);
    const float4* wp = (const float4*)wr;
    float acc = 0.f;
    #pragma unroll
    for (int it = 0; it < 2; ++it) {
        int i = threadIdx.x + it * 256;
        float4 v = hp[i];
        op[i] = v;
        float4 w = wp[i];
        acc += v.x * w.x + v.y * w.y + v.z * w.z + v.w * w.w;
    }
    for (int off = 32; off > 0; off >>= 1) acc += __shfl_down(acc, off, 64);
    __shared__ float s[4];
    int wave = threadIdx.x >> 6, lane = threadIdx.x & 63;
    if (lane == 0) s[wave] = acc;
    __syncthreads();
    if (threadIdx.x == 0) logits[tok] = s[0] + s[1] + s[2] + s[3];
}

// ---------------- fp32 [R][C] -> bf16 [C][R] transpose ----------------
__global__ void transpose_f32_bf16(const float* __restrict__ in, short* __restrict__ out,
                                   int R, int C) {
    __shared__ float tile[32][33];
    int bc = blockIdx.x * 32;
    int br = blockIdx.y * 32;
    int tx = threadIdx.x, ty = threadIdx.y; // 32 x 8
    #pragma unroll
    for (int i = 0; i < 4; ++i)
        tile[ty + i * 8][tx] = in[(size_t)(br + ty + i * 8) * C + bc + tx];
    __syncthreads();
    #pragma unroll
    for (int i = 0; i < 4; ++i)
        out[(size_t)(bc + ty + i * 8) * R + br + tx] = f2bf(tile[tx][ty + i * 8]);
}

// ---------------- exact top-k selection + z-loss (1 block / batch, 1024 thr) ----------------
__global__ void select_kernel(const float* __restrict__ logits, int* __restrict__ sel,
                              float* __restrict__ wts, float* __restrict__ zbuf,
                              float* __restrict__ sel_out_f) {
    int b = blockIdx.x;
    int t = threadIdx.x;              // 0..1023, owns indices 4t..4t+3
    int lane = t & 63, wave = t >> 6;
    __shared__ float smax[16];
    __shared__ float ssum[16];
    __shared__ int   ired[16];
    __shared__ int   wsum[16];

    const float* lg = logits + (size_t)b * S_;
    float4 lv = ((const float4*)lg)[t];
    float l[4] = {lv.x, lv.y, lv.z, lv.w};
    float pm[4];
    unsigned k[4];
    #pragma unroll
    for (int q = 0; q < 4; ++q) {
        pm[q] = ALPHA / (1.f + __expf(-l[q]));
        k[q]  = __float_as_uint(pm[q]);   // probs > 0 -> uint order == float order
    }

    // ---- logsumexp over logits ----
    float m = fmaxf(fmaxf(l[0], l[1]), fmaxf(l[2], l[3]));
    for (int off = 32; off > 0; off >>= 1) m = fmaxf(m, __shfl_down(m, off, 64));
    if (lane == 0) smax[wave] = m;
    __syncthreads();
    float M = smax[0];
    #pragma unroll
    for (int w = 1; w < 16; ++w) M = fmaxf(M, smax[w]);
    float se = __expf(l[0] - M) + __expf(l[1] - M) + __expf(l[2] - M) + __expf(l[3] - M);
    for (int off = 32; off > 0; off >>= 1) se += __shfl_down(se, off, 64);
    __syncthreads();
    if (lane == 0) ssum[wave] = se;
    __syncthreads();
    if (t == 0) {
        float tot = 0.f;
        for (int w = 0; w < 16; ++w) tot += ssum[w];
        zbuf[b] = M + __logf(tot);
    }

    // ---- binary search: smallest T with count(key > T) < KTOP ----
    unsigned lo = 0u, hi = 0x3F000000u;  // 0.5 > alpha upper bound
    while (lo < hi) {
        unsigned mid = (lo + hi) >> 1;
        int c = (k[0] > mid) + (k[1] > mid) + (k[2] > mid) + (k[3] > mid);
        for (int off = 32; off > 0; off >>= 1) c += __shfl_down(c, off, 64);
        __syncthreads();
        if (lane == 0) ired[wave] = c;
        __syncthreads();
        int tot = 0;
        #pragma unroll
        for (int w = 0; w < 16; ++w) tot += ired[w];
        if (tot < KTOP) hi = mid; else lo = mid + 1;
    }
    unsigned T = lo;

    // ---- g = count(key > T); r = slots left for ties (taken in ascending index order) ----
    {
        int c = (k[0] > T) + (k[1] > T) + (k[2] > T) + (k[3] > T);
        for (int off = 32; off > 0; off >>= 1) c += __shfl_down(c, off, 64);
        __syncthreads();
        if (lane == 0) ired[wave] = c;
        __syncthreads();
    }
    int g = 0;
    #pragma unroll
    for (int w = 0; w < 16; ++w) g += ired[w];
    int r = KTOP - g;

    int gt[4], eq[4];
    #pragma unroll
    for (int q = 0; q < 4; ++q) { gt[q] = (k[q] > T); eq[q] = (k[q] == T); }

    // exclusive scan of per-thread eq count
    int eqc = eq[0] + eq[1] + eq[2] + eq[3];
    int x = eqc;
    for (int off = 1; off < 64; off <<= 1) {
        int y = __shfl_up(x, off, 64);
        if (lane >= off) x += y;
    }
    __syncthreads();
    if (lane == 63) wsum[wave] = x;
    __syncthreads();
    int woff = 0;
    for (int w = 0; w < wave; ++w) woff += wsum[w];
    int run = woff + x - eqc;   // exclusive eq rank at my first index

    int flag[4];
    #pragma unroll
    for (int q = 0; q < 4; ++q) {
        flag[q] = gt[q] | (eq[q] & (run < r ? 1 : 0));
        run += eq[q];
    }

    // exclusive scan of per-thread selected count -> output position
    int fc = flag[0] + flag[1] + flag[2] + flag[3];
    int x2 = fc;
    for (int off = 1; off < 64; off <<= 1) {
        int y = __shfl_up(x2, off, 64);
        if (lane >= off) x2 += y;
    }
    __syncthreads();
    if (lane == 63) wsum[wave] = x2;
    __syncthreads();
    int woff2 = 0;
    for (int w = 0; w < wave; ++w) woff2 += wsum[w];
    int pos = woff2 + x2 - fc;

    #pragma unroll
    for (int q = 0; q < 4; ++q) {
        if (flag[q]) {
            int idx = t * 4 + q;
            sel[b * KTOP + pos]       = idx;
            wts[b * KTOP + pos]       = pm[q];
            sel_out_f[b * KTOP + pos] = (float)idx;
            pos++;
        }
    }
}

__global__ void zloss_kernel(const float* __restrict__ zbuf, float* __restrict__ out_scalar) {
    if (threadIdx.x == 0) {
        float s = 0.f;
        for (int b = 0; b < B_; ++b) { float z = zbuf[b]; s += z * z; }
        out_scalar[0] = s * (1.f / B_);
    }
}

// ---------------- gather selected tokens -> bf16 X [B*KTOP][D] ----------------
__global__ void gather_kernel(const float* __restrict__ h, const int* __restrict__ sel,
                              short* __restrict__ X) {
    int rrow = blockIdx.x;            // 0..B*KTOP-1
    int b = rrow >> 11;               // KTOP == 2048
    int s = sel[rrow];
    const float4* src = (const float4*)(h + ((size_t)b * S_ + s) * D_);
    short8* dst = (short8*)(X + (size_t)rrow * D_);
    int i = threadIdx.x;              // 256 threads * 8 elems
    float4 v0 = src[i * 2], v1 = src[i * 2 + 1];
    short8 o;
    o[0] = f2bf(v0.x); o[1] = f2bf(v0.y); o[2] = f2bf(v0.z); o[3] = f2bf(v0.w);
    o[4] = f2bf(v1.x); o[5] = f2bf(v1.y); o[6] = f2bf(v1.z); o[7] = f2bf(v1.w);
    dst[i] = o;
}

// ---- GEMM1: H[:,fslice] = silu(X @ W1[:,fslice]) ; A [M][K] bf16, Bt [N][K] bf16 slice ----
__global__ void gemm_ffn1(const short* __restrict__ A, const short* __restrict__ Bt,
                          short* __restrict__ H, int M, int N, int K) {
    __shared__ alignas(16) short As[128 * 32];
    __shared__ alignas(16) short Bs[128 * 32];
    int tid = threadIdx.x;
    int lane = tid & 63, wave = tid >> 6;
    int bm = blockIdx.y * 128, bn = blockIdx.x * 128;
    int wr = (wave >> 1) * 64, wc = (wave & 1) * 64;
    floatx4 zero = {0.f, 0.f, 0.f, 0.f};
    floatx4 acc[4][4];
    #pragma unroll
    for (int mm = 0; mm < 4; ++mm)
        #pragma unroll
        for (int nn = 0; nn < 4; ++nn) acc[mm][nn] = zero;

    const short* gA0 = A  + (size_t)(bm + (tid >> 2)) * K + (tid & 3) * 8;
    const short* gA1 = A  + (size_t)(bm + (tid >> 2) + 64) * K + (tid & 3) * 8;
    const short* gB0 = Bt + (size_t)(bn + (tid >> 2)) * K + (tid & 3) * 8;
    const short* gB1 = Bt + (size_t)(bn + (tid >> 2) + 64) * K + (tid & 3) * 8;

    for (int k0 = 0; k0 < K; k0 += 32) {
        __builtin_amdgcn_global_load_lds((gas_ptr)(gA0 + k0), (las_ptr)&As[tid * 8], 16, 0, 0);
        __builtin_amdgcn_global_load_lds((gas_ptr)(gA1 + k0), (las_ptr)&As[(tid + 256) * 8], 16, 0, 0);
        __builtin_amdgcn_global_load_lds((gas_ptr)(gB0 + k0), (las_ptr)&Bs[tid * 8], 16, 0, 0);
        __builtin_amdgcn_global_load_lds((gas_ptr)(gB1 + k0), (las_ptr)&Bs[(tid + 256) * 8], 16, 0, 0);
        __syncthreads();
        short8 a[4], bb[4];
        #pragma unroll
        for (int mm = 0; mm < 4; ++mm)
            a[mm] = *(const short8*)&As[(wr + mm * 16 + (lane & 15)) * 32 + (lane >> 4) * 8];
        #pragma unroll
        for (int nn = 0; nn < 4; ++nn)
            bb[nn] = *(const short8*)&Bs[(wc + nn * 16 + (lane & 15)) * 32 + (lane >> 4) * 8];
        #pragma unroll
        for (int mm = 0; mm < 4; ++mm)
            #pragma unroll
            for (int nn = 0; nn < 4; ++nn)
                acc[mm][nn] = __builtin_amdgcn_mfma_f32_16x16x32_bf16(a[mm], bb[nn], acc[mm][nn], 0, 0, 0);
        __syncthreads();
    }

    int cl = lane & 15, r0 = (lane >> 4) * 4;
    #pragma unroll
    for (int mm = 0; mm < 4; ++mm)
        #pragma unroll
        for (int nn = 0; nn < 4; ++nn)
            #pragma unroll
            for (int i = 0; i < 4; ++i) {
                float v = acc[mm][nn][i];
                v = v / (1.f + __expf(-v));      // silu
                int gr = bm + wr + mm * 16 + r0 + i;
                int gc = bn + wc + nn * 16 + cl;
                H[(size_t)gr * N + gc] = f2bf(v);
            }
}

// ---- GEMM2 (F-chunked split-K) + gate + scatter-add:
//      out[b,sel[row],:] += (H_chunk @ W2[fslice,:] + (add_res ? X : 0)) * w[row]
//      A [M][lda] bf16, Bt rows stride ldb ----
__global__ void gemm_ffn2_scatter(const short* __restrict__ A, const short* __restrict__ Bt,
                                  const short* __restrict__ Xc, const int* __restrict__ sel,
                                  const float* __restrict__ wts, float* __restrict__ out,
                                  int K, int lda, int ldb, int add_res) {
    __shared__ alignas(16) short As[128 * 32];
    __shared__ alignas(16) short Bs[128 * 32];
    int tid = threadIdx.x;
    int lane = tid & 63, wave = tid >> 6;
    int bm = blockIdx.y * 128, bn = blockIdx.x * 128;
    int wr = (wave >> 1) * 64, wc = (wave & 1) * 64;
    floatx4 zero = {0.f, 0.f, 0.f, 0.f};
    floatx4 acc[4][4];
    #pragma unroll
    for (int mm = 0; mm < 4; ++mm)
        #pragma unroll
        for (int nn = 0; nn < 4; ++nn) acc[mm][nn] = zero;

    const short* gA0 = A  + (size_t)(bm + (tid >> 2)) * lda + (tid & 3) * 8;
    const short* gA1 = A  + (size_t)(bm + (tid >> 2) + 64) * lda + (tid & 3) * 8;
    const short* gB0 = Bt + (size_t)(bn + (tid >> 2)) * ldb + (tid & 3) * 8;
    const short* gB1 = Bt + (size_t)(bn + (tid >> 2) + 64) * ldb + (tid & 3) * 8;

    for (int k0 = 0; k0 < K; k0 += 32) {
        __builtin_amdgcn_global_load_lds((gas_ptr)(gA0 + k0), (las_ptr)&As[tid * 8], 16, 0, 0);
        __builtin_amdgcn_global_load_lds((gas_ptr)(gA1 + k0), (las_ptr)&As[(tid + 256) * 8], 16, 0, 0);
        __builtin_amdgcn_global_load_lds((gas_ptr)(gB0 + k0), (las_ptr)&Bs[tid * 8], 16, 0, 0);
        __builtin_amdgcn_global_load_lds((gas_ptr)(gB1 + k0), (las_ptr)&Bs[(tid + 256) * 8], 16, 0, 0);
        __syncthreads();
        short8 a[4], bb[4];
        #pragma unroll
        for (int mm = 0; mm < 4; ++mm)
            a[mm] = *(const short8*)&As[(wr + mm * 16 + (lane & 15)) * 32 + (lane >> 4) * 8];
        #pragma unroll
        for (int nn = 0; nn < 4; ++nn)
            bb[nn] = *(const short8*)&Bs[(wc + nn * 16 + (lane & 15)) * 32 + (lane >> 4) * 8];
        #pragma unroll
        for (int mm = 0; mm < 4; ++mm)
            #pragma unroll
            for (int nn = 0; nn < 4; ++nn)
                acc[mm][nn] = __builtin_amdgcn_mfma_f32_16x16x32_bf16(a[mm], bb[nn], acc[mm][nn], 0, 0, 0);
        __syncthreads();
    }

    int cl = lane & 15, r0 = (lane >> 4) * 4;
    #pragma unroll
    for (int mm = 0; mm < 4; ++mm)
        #pragma unroll
        for (int nn = 0; nn < 4; ++nn)
            #pragma unroll
            for (int i = 0; i < 4; ++i) {
                int row = bm + wr + mm * 16 + r0 + i;     // compact token row 0..8191
                int col = bn + wc + nn * 16 + cl;         // 0..2047
                float v = acc[mm][nn][i];
                if (add_res) v += bf2f(Xc[(size_t)row * D_ + col]);
                v *= wts[row];
                int s = sel[row];
                int bloc = row >> 11;                     // KTOP == 2048 rows per batch
                float* o = out + ((size_t)bloc * S_ + s) * D_ + col;
                *o += v;                                  // chunk launches are stream-serialized
            }
}

extern "C" void kernel_launch(void* const* d_in, const int* in_sizes, int n_in,
                              void* d_out, int out_size, void* d_ws, size_t ws_size,
                              hipStream_t stream) {
    const float* h   = (const float*)d_in[0];
    const float* wrt = (const float*)d_in[1];
    const float* w1  = (const float*)d_in[2];
    const float* w2  = (const float*)d_in[3];
    float* out = (float*)d_out;

    char* ws = (char*)d_ws;
    size_t off = 0;
    auto alloc = [&](size_t bytes) -> void* {
        void* p = ws + off;
        off = (off + bytes + 255) & ~(size_t)255;
        return p;
    };
    float* logits = (float*)alloc((size_t)B_ * S_ * 4);
    float* zbuf   = (float*)alloc(16 * 4);
    int*   sel_i  = (int*)alloc((size_t)B_ * KTOP * 4);
    float* wts    = (float*)alloc((size_t)B_ * KTOP * 4);
    short* w1t    = (short*)alloc((size_t)D_ * F_ * 2);
    short* w2t    = (short*)alloc((size_t)D_ * F_ * 2);
    short* X      = (short*)alloc((size_t)B_ * KTOP * D_ * 2);
    short* H      = (short*)alloc((size_t)B_ * KTOP * (F_ / 2) * 2);  // 8192 x 4096 F-chunk

    float* out_z   = out + (size_t)B_ * S_ * D_;
    float* out_sel = out_z + 1;

    router_copy_kernel<<<B_ * S_, 256, 0, stream>>>(h, wrt, out, logits);
    dim3 tb(32, 8);
    transpose_f32_bf16<<<dim3(F_ / 32, D_ / 32), tb, 0, stream>>>(w1, w1t, D_, F_);
    transpose_f32_bf16<<<dim3(D_ / 32, F_ / 32), tb, 0, stream>>>(w2, w2t, F_, D_);
    select_kernel<<<B_, 1024, 0, stream>>>(logits, sel_i, wts, zbuf, out_sel);
    zloss_kernel<<<1, 64, 0, stream>>>(zbuf, out_z);
    gather_kernel<<<B_ * KTOP, 256, 0, stream>>>(h, sel_i, X);

    const int MTOT = B_ * KTOP;     // 8192 compact tokens
    const int FC   = F_ / 2;        // 4096 F-columns per chunk
    for (int c = 0; c < 2; ++c) {
        const short* w1c = w1t + (size_t)c * FC * D_;   // w1t rows [c*FC, (c+1)*FC) of [F][D]
        const short* w2c = w2t + (size_t)c * FC;        // w2t cols [c*FC, ...) of [D][F]
        gemm_ffn1<<<dim3(FC / 128, MTOT / 128), 256, 0, stream>>>(X, w1c, H, MTOT, FC, D_);
        gemm_ffn2_scatter<<<dim3(D_ / 128, MTOT / 128), 256, 0, stream>>>(
            H, w2c, X, sel_i, wts, out, FC, FC, F_, c == 0);
    }
}

// Round 10
// 1083.866 us; speedup vs baseline: 1.0299x; 1.0299x over previous
//
#include <hip/hip_runtime.h>
#include <hip/hip_bf16.h>
#include <math.h>

#define B_    4
#define S_    4096
#define D_    2048
#define F_    8192
#define KTOP  2048
#define ALPHA 0.1f

typedef __attribute__((ext_vector_type(8))) short short8;
typedef __attribute__((ext_vector_type(4))) float floatx4;

typedef const __attribute__((address_space(1))) void* gas_ptr;
typedef __attribute__((address_space(3))) void* las_ptr;

__device__ __forceinline__ short f2bf(float f) {
    unsigned u = __float_as_uint(f);
    unsigned r = u + 0x7FFFu + ((u >> 16) & 1u);
    return (short)(r >> 16);
}
__device__ __forceinline__ float bf2f(short s) {
    return __uint_as_float(((unsigned)(unsigned short)s) << 16);
}

// ---------------- router logits + copy hidden -> out ----------------
__global__ void router_copy_kernel(const float* __restrict__ h, const float* __restrict__ wr,
                                   float* __restrict__ out, float* __restrict__ logits) {
    int tok = blockIdx.x;
    const float4* hp = (const float4*)(h + (size_t)tok * D_);
    float4* op = (float4*)(out + (size_t)tok * D_);
    const float4* wp = (const float4*)wr;
    float acc = 0.f;
    #pragma unroll
    for (int it = 0; it < 2; ++it) {
        int i = threadIdx.x + it * 256;
        float4 v = hp[i];
        op[i] = v;
        float4 w = wp[i];
        acc += v.x * w.x + v.y * w.y + v.z * w.z + v.w * w.w;
    }
    for (int off = 32; off > 0; off >>= 1) acc += __shfl_down(acc, off, 64);
    __shared__ float s[4];
    int wave = threadIdx.x >> 6, lane = threadIdx.x & 63;
    if (lane == 0) s[wave] = acc;
    __syncthreads();
    if (threadIdx.x == 0) logits[tok] = s[0] + s[1] + s[2] + s[3];
}

// ---------------- fp32 [R][C] -> bf16 [C][R] transpose ----------------
__global__ void transpose_f32_bf16(const float* __restrict__ in, short* __restrict__ out,
                                   int R, int C) {
    __shared__ float tile[32][33];
    int bc = blockIdx.x * 32;
    int br = blockIdx.y * 32;
    int tx = threadIdx.x, ty = threadIdx.y; // 32 x 8
    #pragma unroll
    for (int i = 0; i < 4; ++i)
        tile[ty + i * 8][tx] = in[(size_t)(br + ty + i * 8) * C + bc + tx];
    __syncthreads();
    #pragma unroll
    for (int i = 0; i < 4; ++i)
        out[(size_t)(bc + ty + i * 8) * R + br + tx] = f2bf(tile[tx][ty + i * 8]);
}

// ---------------- exact top-k selection + z-loss (1 block / batch, 1024 thr) ----------------
__global__ void select_kernel(const float* __restrict__ logits, int* __restrict__ sel,
                              float* __restrict__ wts, float* __restrict__ zbuf,
                              float* __restrict__ sel_out_f) {
    int b = blockIdx.x;
    int t = threadIdx.x;              // 0..1023, owns indices 4t..4t+3
    int lane = t & 63, wave = t >> 6;
    __shared__ float smax[16];
    __shared__ float ssum[16];
    __shared__ int   ired[16];
    __shared__ int   wsum[16];

    const float* lg = logits + (size_t)b * S_;
    float4 lv = ((const float4*)lg)[t];
    float l[4] = {lv.x, lv.y, lv.z, lv.w};
    float pm[4];
    unsigned k[4];
    #pragma unroll
    for (int q = 0; q < 4; ++q) {
        pm[q] = ALPHA / (1.f + __expf(-l[q]));
        k[q]  = __float_as_uint(pm[q]);   // probs > 0 -> uint order == float order
    }

    // ---- logsumexp over logits ----
    float m = fmaxf(fmaxf(l[0], l[1]), fmaxf(l[2], l[3]));
    for (int off = 32; off > 0; off >>= 1) m = fmaxf(m, __shfl_down(m, off, 64));
    if (lane == 0) smax[wave] = m;
    __syncthreads();
    float M = smax[0];
    #pragma unroll
    for (int w = 1; w < 16; ++w) M = fmaxf(M, smax[w]);
    float se = __expf(l[0] - M) + __expf(l[1] - M) + __expf(l[2] - M) + __expf(l[3] - M);
    for (int off = 32; off > 0; off >>= 1) se += __shfl_down(se, off, 64);
    __syncthreads();
    if (lane == 0) ssum[wave] = se;
    __syncthreads();
    if (t == 0) {
        float tot = 0.f;
        for (int w = 0; w < 16; ++w) tot += ssum[w];
        zbuf[b] = M + __logf(tot);
    }

    // ---- binary search: smallest T with count(key > T) < KTOP ----
    unsigned lo = 0u, hi = 0x3F000000u;  // 0.5 > alpha upper bound
    while (lo < hi) {
        unsigned mid = (lo + hi) >> 1;
        int c = (k[0] > mid) + (k[1] > mid) + (k[2] > mid) + (k[3] > mid);
        for (int off = 32; off > 0; off >>= 1) c += __shfl_down(c, off, 64);
        __syncthreads();
        if (lane == 0) ired[wave] = c;
        __syncthreads();
        int tot = 0;
        #pragma unroll
        for (int w = 0; w < 16; ++w) tot += ired[w];
        if (tot < KTOP) hi = mid; else lo = mid + 1;
    }
    unsigned T = lo;

    // ---- g = count(key > T); r = slots left for ties (taken in ascending index order) ----
    {
        int c = (k[0] > T) + (k[1] > T) + (k[2] > T) + (k[3] > T);
        for (int off = 32; off > 0; off >>= 1) c += __shfl_down(c, off, 64);
        __syncthreads();
        if (lane == 0) ired[wave] = c;
        __syncthreads();
    }
    int g = 0;
    #pragma unroll
    for (int w = 0; w < 16; ++w) g += ired[w];
    int r = KTOP - g;

    int gt[4], eq[4];
    #pragma unroll
    for (int q = 0; q < 4; ++q) { gt[q] = (k[q] > T); eq[q] = (k[q] == T); }

    // exclusive scan of per-thread eq count
    int eqc = eq[0] + eq[1] + eq[2] + eq[3];
    int x = eqc;
    for (int off = 1; off < 64; off <<= 1) {
        int y = __shfl_up(x, off, 64);
        if (lane >= off) x += y;
    }
    __syncthreads();
    if (lane == 63) wsum[wave] = x;
    __syncthreads();
    int woff = 0;
    for (int w = 0; w < wave; ++w) woff += wsum[w];
    int run = woff + x - eqc;   // exclusive eq rank at my first index

    int flag[4];
    #pragma unroll
    for (int q = 0; q < 4; ++q) {
        flag[q] = gt[q] | (eq[q] & (run < r ? 1 : 0));
        run += eq[q];
    }

    // exclusive scan of per-thread selected count -> output position
    int fc = flag[0] + flag[1] + flag[2] + flag[3];
    int x2 = fc;
    for (int off = 1; off < 64; off <<= 1) {
        int y = __shfl_up(x2, off, 64);
        if (lane >= off) x2 += y;
    }
    __syncthreads();
    if (lane == 63) wsum[wave] = x2;
    __syncthreads();
    int woff2 = 0;
    for (int w = 0; w < wave; ++w) woff2 += wsum[w];
    int pos = woff2 + x2 - fc;

    #pragma unroll
    for (int q = 0; q < 4; ++q) {
        if (flag[q]) {
            int idx = t * 4 + q;
            sel[b * KTOP + pos]       = idx;
            wts[b * KTOP + pos]       = pm[q];
            sel_out_f[b * KTOP + pos] = (float)idx;
            pos++;
        }
    }
}

__global__ void zloss_kernel(const float* __restrict__ zbuf, float* __restrict__ out_scalar) {
    if (threadIdx.x == 0) {
        float s = 0.f;
        for (int b = 0; b < B_; ++b) { float z = zbuf[b]; s += z * z; }
        out_scalar[0] = s * (1.f / B_);
    }
}

// ---------------- gather selected tokens -> bf16 X [B*KTOP][D] ----------------
__global__ void gather_kernel(const float* __restrict__ h, const int* __restrict__ sel,
                              short* __restrict__ X) {
    int rrow = blockIdx.x;            // 0..B*KTOP-1
    int b = rrow >> 11;               // KTOP == 2048
    int s = sel[rrow];
    const float4* src = (const float4*)(h + ((size_t)b * S_ + s) * D_);
    short8* dst = (short8*)(X + (size_t)rrow * D_);
    int i = threadIdx.x;              // 256 threads * 8 elems
    float4 v0 = src[i * 2], v1 = src[i * 2 + 1];
    short8 o;
    o[0] = f2bf(v0.x); o[1] = f2bf(v0.y); o[2] = f2bf(v0.z); o[3] = f2bf(v0.w);
    o[4] = f2bf(v1.x); o[5] = f2bf(v1.y); o[6] = f2bf(v1.z); o[7] = f2bf(v1.w);
    dst[i] = o;
}

// LDS slot swizzle (both GEMMs): LDS dest stays linear (global_load_lds rule),
// global SOURCE k-slot is permuted slot' = slot ^ ((row>>1)&3), and the
// fragment read XORs the same: spreads a 16-lane group over 8 bank-groups
// (was 2 -> 8-way conflict; now 2-way = free per m136).

// ---- GEMM1: H[:,fslice] = silu(X @ W1[:,fslice]) ; A [M][K] bf16, Bt [N][K] bf16 slice ----
__global__ void gemm_ffn1(const short* __restrict__ A, const short* __restrict__ Bt,
                          short* __restrict__ H, int M, int N, int K) {
    __shared__ alignas(16) short As[128 * 32];
    __shared__ alignas(16) short Bs[128 * 32];
    int tid = threadIdx.x;
    int lane = tid & 63, wave = tid >> 6;
    int bm = blockIdx.y * 128, bn = blockIdx.x * 128;
    int wr = (wave >> 1) * 64, wc = (wave & 1) * 64;
    floatx4 zero = {0.f, 0.f, 0.f, 0.f};
    floatx4 acc[4][4];
    #pragma unroll
    for (int mm = 0; mm < 4; ++mm)
        #pragma unroll
        for (int nn = 0; nn < 4; ++nn) acc[mm][nn] = zero;

    int srow  = tid >> 2;
    int sslot = (tid & 3) ^ ((tid >> 3) & 3);          // pre-swizzled global k-slot
    const short* gA0 = A  + (size_t)(bm + srow) * K + sslot * 8;
    const short* gA1 = A  + (size_t)(bm + srow + 64) * K + sslot * 8;
    const short* gB0 = Bt + (size_t)(bn + srow) * K + sslot * 8;
    const short* gB1 = Bt + (size_t)(bn + srow + 64) * K + sslot * 8;

    int xslot = (((lane >> 4) ^ ((lane >> 1) & 3)) * 8);  // swizzled read slot (shorts)

    for (int k0 = 0; k0 < K; k0 += 32) {
        __builtin_amdgcn_global_load_lds((gas_ptr)(gA0 + k0), (las_ptr)&As[tid * 8], 16, 0, 0);
        __builtin_amdgcn_global_load_lds((gas_ptr)(gA1 + k0), (las_ptr)&As[(tid + 256) * 8], 16, 0, 0);
        __builtin_amdgcn_global_load_lds((gas_ptr)(gB0 + k0), (las_ptr)&Bs[tid * 8], 16, 0, 0);
        __builtin_amdgcn_global_load_lds((gas_ptr)(gB1 + k0), (las_ptr)&Bs[(tid + 256) * 8], 16, 0, 0);
        __syncthreads();
        short8 a[4], bb[4];
        #pragma unroll
        for (int mm = 0; mm < 4; ++mm)
            a[mm] = *(const short8*)&As[(wr + mm * 16 + (lane & 15)) * 32 + xslot];
        #pragma unroll
        for (int nn = 0; nn < 4; ++nn)
            bb[nn] = *(const short8*)&Bs[(wc + nn * 16 + (lane & 15)) * 32 + xslot];
        #pragma unroll
        for (int mm = 0; mm < 4; ++mm)
            #pragma unroll
            for (int nn = 0; nn < 4; ++nn)
                acc[mm][nn] = __builtin_amdgcn_mfma_f32_16x16x32_bf16(a[mm], bb[nn], acc[mm][nn], 0, 0, 0);
        __syncthreads();
    }

    int cl = lane & 15, r0 = (lane >> 4) * 4;
    #pragma unroll
    for (int mm = 0; mm < 4; ++mm)
        #pragma unroll
        for (int nn = 0; nn < 4; ++nn)
            #pragma unroll
            for (int i = 0; i < 4; ++i) {
                float v = acc[mm][nn][i];
                v = v / (1.f + __expf(-v));      // silu
                int gr = bm + wr + mm * 16 + r0 + i;
                int gc = bn + wc + nn * 16 + cl;
                H[(size_t)gr * N + gc] = f2bf(v);
            }
}

// ---- GEMM2 (F-chunked split-K) + gate + scatter-add:
//      out[b,sel[row],:] += (H_chunk @ W2[fslice,:] + (add_res ? X : 0)) * w[row]
//      A [M][lda] bf16, Bt rows stride ldb ----
__global__ void gemm_ffn2_scatter(const short* __restrict__ A, const short* __restrict__ Bt,
                                  const short* __restrict__ Xc, const int* __restrict__ sel,
                                  const float* __restrict__ wts, float* __restrict__ out,
                                  int K, int lda, int ldb, int add_res) {
    __shared__ alignas(16) short As[128 * 32];
    __shared__ alignas(16) short Bs[128 * 32];
    int tid = threadIdx.x;
    int lane = tid & 63, wave = tid >> 6;
    int bm = blockIdx.y * 128, bn = blockIdx.x * 128;
    int wr = (wave >> 1) * 64, wc = (wave & 1) * 64;
    floatx4 zero = {0.f, 0.f, 0.f, 0.f};
    floatx4 acc[4][4];
    #pragma unroll
    for (int mm = 0; mm < 4; ++mm)
        #pragma unroll
        for (int nn = 0; nn < 4; ++nn) acc[mm][nn] = zero;

    int srow  = tid >> 2;
    int sslot = (tid & 3) ^ ((tid >> 3) & 3);
    const short* gA0 = A  + (size_t)(bm + srow) * lda + sslot * 8;
    const short* gA1 = A  + (size_t)(bm + srow + 64) * lda + sslot * 8;
    const short* gB0 = Bt + (size_t)(bn + srow) * ldb + sslot * 8;
    const short* gB1 = Bt + (size_t)(bn + srow + 64) * ldb + sslot * 8;

    int xslot = (((lane >> 4) ^ ((lane >> 1) & 3)) * 8);

    for (int k0 = 0; k0 < K; k0 += 32) {
        __builtin_amdgcn_global_load_lds((gas_ptr)(gA0 + k0), (las_ptr)&As[tid * 8], 16, 0, 0);
        __builtin_amdgcn_global_load_lds((gas_ptr)(gA1 + k0), (las_ptr)&As[(tid + 256) * 8], 16, 0, 0);
        __builtin_amdgcn_global_load_lds((gas_ptr)(gB0 + k0), (las_ptr)&Bs[tid * 8], 16, 0, 0);
        __builtin_amdgcn_global_load_lds((gas_ptr)(gB1 + k0), (las_ptr)&Bs[(tid + 256) * 8], 16, 0, 0);
        __syncthreads();
        short8 a[4], bb[4];
        #pragma unroll
        for (int mm = 0; mm < 4; ++mm)
            a[mm] = *(const short8*)&As[(wr + mm * 16 + (lane & 15)) * 32 + xslot];
        #pragma unroll
        for (int nn = 0; nn < 4; ++nn)
            bb[nn] = *(const short8*)&Bs[(wc + nn * 16 + (lane & 15)) * 32 + xslot];
        #pragma unroll
        for (int mm = 0; mm < 4; ++mm)
            #pragma unroll
            for (int nn = 0; nn < 4; ++nn)
                acc[mm][nn] = __builtin_amdgcn_mfma_f32_16x16x32_bf16(a[mm], bb[nn], acc[mm][nn], 0, 0, 0);
        __syncthreads();
    }

    int cl = lane & 15, r0 = (lane >> 4) * 4;
    #pragma unroll
    for (int mm = 0; mm < 4; ++mm)
        #pragma unroll
        for (int nn = 0; nn < 4; ++nn)
            #pragma unroll
            for (int i = 0; i < 4; ++i) {
                int row = bm + wr + mm * 16 + r0 + i;     // compact token row 0..8191
                int col = bn + wc + nn * 16 + cl;         // 0..2047
                float v = acc[mm][nn][i];
                if (add_res) v += bf2f(Xc[(size_t)row * D_ + col]);
                v *= wts[row];
                int s = sel[row];
                int bloc = row >> 11;                     // KTOP == 2048 rows per batch
                float* o = out + ((size_t)bloc * S_ + s) * D_ + col;
                *o += v;                                  // chunk launches are stream-serialized
            }
}

extern "C" void kernel_launch(void* const* d_in, const int* in_sizes, int n_in,
                              void* d_out, int out_size, void* d_ws, size_t ws_size,
                              hipStream_t stream) {
    const float* h   = (const float*)d_in[0];
    const float* wrt = (const float*)d_in[1];
    const float* w1  = (const float*)d_in[2];
    const float* w2  = (const float*)d_in[3];
    float* out = (float*)d_out;

    char* ws = (char*)d_ws;
    size_t off = 0;
    auto alloc = [&](size_t bytes) -> void* {
        void* p = ws + off;
        off = (off + bytes + 255) & ~(size_t)255;
        return p;
    };
    float* logits = (float*)alloc((size_t)B_ * S_ * 4);
    float* zbuf   = (float*)alloc(16 * 4);
    int*   sel_i  = (int*)alloc((size_t)B_ * KTOP * 4);
    float* wts    = (float*)alloc((size_t)B_ * KTOP * 4);
    short* w1t    = (short*)alloc((size_t)D_ * F_ * 2);
    short* w2t    = (short*)alloc((size_t)D_ * F_ * 2);
    short* X      = (short*)alloc((size_t)B_ * KTOP * D_ * 2);
    short* H      = (short*)alloc((size_t)B_ * KTOP * (F_ / 2) * 2);  // 8192 x 4096 F-chunk

    float* out_z   = out + (size_t)B_ * S_ * D_;
    float* out_sel = out_z + 1;

    router_copy_kernel<<<B_ * S_, 256, 0, stream>>>(h, wrt, out, logits);
    dim3 tb(32, 8);
    transpose_f32_bf16<<<dim3(F_ / 32, D_ / 32), tb, 0, stream>>>(w1, w1t, D_, F_);
    transpose_f32_bf16<<<dim3(D_ / 32, F_ / 32), tb, 0, stream>>>(w2, w2t, F_, D_);
    select_kernel<<<B_, 1024, 0, stream>>>(logits, sel_i, wts, zbuf, out_sel);
    zloss_kernel<<<1, 64, 0, stream>>>(zbuf, out_z);
    gather_kernel<<<B_ * KTOP, 256, 0, stream>>>(h, sel_i, X);

    const int MTOT = B_ * KTOP;     // 8192 compact tokens
    const int FC   = F_ / 2;        // 4096 F-columns per chunk
    for (int c = 0; c < 2; ++c) {
        const short* w1c = w1t + (size_t)c * FC * D_;   // w1t rows [c*FC, (c+1)*FC) of [F][D]
        const short* w2c = w2t + (size_t)c * FC;        // w2t cols [c*FC, ...) of [D][F]
        gemm_ffn1<<<dim3(FC / 128, MTOT / 128), 256, 0, stream>>>(X, w1c, H, MTOT, FC, D_);
        gemm_ffn2_scatter<<<dim3(D_ / 128, MTOT / 128), 256, 0, stream>>>(
            H, w2c, X, sel_i, wts, out, FC, FC, F_, c == 0);
    }
}